// Round 13
// baseline (104.295 us; speedup 1.0000x reference)
//
#include <hip/hip_runtime.h>
#include <hip/hip_bf16.h>
#include <stdint.h>

#define B_ 8
#define C_ 512
#define T_ 4096
#define O_ 512
#define KP_ 1728   /* padded K: 3 groups x 3 k x 192 */
#define EPS_ 1e-8f

#define BM 256
#define BN 256
#define FTP_ROWS 4104

/* LDS: 2 buffers x [A-h0 8192 | A-h1 8192 | B-h0 8192 | B-h1 8192] ush = 128 KB */
#define BUF_USH 32768
#define LDS_BYTES (2 * BUF_USH * 2)

typedef unsigned short ushort_t;
typedef __attribute__((ext_vector_type(4))) float f32x4;
typedef __attribute__((ext_vector_type(8))) short bf16x8;

__device__ __forceinline__ ushort_t f2bf(float f) {
  union { float f; uint32_t u; } x; x.f = f;
  uint32_t u = x.u;
  uint32_t r = (u + 0x7FFFu + ((u >> 16) & 1u)) >> 16;
  return (ushort_t)r;
}

#define GLOAD16(gsrc, ldst) \
  __builtin_amdgcn_global_load_lds((const __attribute__((address_space(1))) unsigned int*)(gsrc), \
                                   (__attribute__((address_space(3))) unsigned int*)(ldst), 16, 0, 0)

// ---------------- sim reduction: nn[t] = sum_c e^2, dl[t] = sum_c e[t]*e[t-1] ---------
__global__ void sim_reduce_kernel(const float* __restrict__ emb,
                                  float* __restrict__ nn_out,
                                  float* __restrict__ dl_out) {
  const int b = blockIdx.y;
  const int t0 = (blockIdx.x * 64 + threadIdx.x) * 4;
  const int cty = threadIdx.y;
  float nn0=0.f,nn1=0.f,nn2=0.f,nn3=0.f;
  float dl0=0.f,dl1=0.f,dl2=0.f,dl3=0.f;
  const float* base = emb + (size_t)b * C_ * T_;
  for (int c = cty * 128; c < cty * 128 + 128; ++c) {
    const float* row = base + (size_t)c * T_;
    float4 v = *(const float4*)(row + t0);
    float el = (t0 > 0) ? row[t0 - 1] : 0.f;
    nn0 += v.x*v.x; nn1 += v.y*v.y; nn2 += v.z*v.z; nn3 += v.w*v.w;
    dl0 += v.x*el;  dl1 += v.y*v.x; dl2 += v.z*v.y; dl3 += v.w*v.z;
  }
  __shared__ float red[4][64*8];
  float* myr = &red[cty][threadIdx.x * 8];
  if (cty != 0) {
    myr[0]=nn0; myr[1]=nn1; myr[2]=nn2; myr[3]=nn3;
    myr[4]=dl0; myr[5]=dl1; myr[6]=dl2; myr[7]=dl3;
  }
  __syncthreads();
  if (cty == 0) {
    for (int q = 1; q < 4; ++q) {
      float* r = &red[q][threadIdx.x * 8];
      nn0+=r[0]; nn1+=r[1]; nn2+=r[2]; nn3+=r[3];
      dl0+=r[4]; dl1+=r[5]; dl2+=r[6]; dl3+=r[7];
    }
    float* nb = nn_out + (size_t)b * T_ + t0;
    float* db = dl_out + (size_t)b * T_ + t0;
    nb[0]=nn0; nb[1]=nn1; nb[2]=nn2; nb[3]=nn3;
    db[0]=dl0; db[1]=dl1; db[2]=dl2; db[3]=dl3;
  }
}

// ------- fused: Horner-ratio finalize (blocks 0..127) + weight permute (rest) --------
__global__ void prep_small_kernel(const float* __restrict__ nn,
                                  const float* __restrict__ dl,
                                  float* __restrict__ rat,
                                  const float* __restrict__ w,
                                  ushort_t* __restrict__ wbf) {
  const int bid = blockIdx.x;
  if (bid < 128) {
    const int idx = bid * 256 + threadIdx.x;
    const int b = idx >> 12;
    const int t = idx & (T_ - 1);
    const float* nnb = nn + (size_t)b * T_;
    const float* dlb = dl + (size_t)b * T_;
    float nncur = nnb[t];
    float ncur = fmaxf(sqrtf(nncur), EPS_);
    float sc = nncur / (ncur * ncur);
    float sl = 0.f, sr = 0.f;
    if (t > 0) {
      float np = fmaxf(sqrtf(nnb[t - 1]), EPS_);
      sl = dlb[t] / (ncur * np);
    }
    if (t < T_ - 1) {
      float nx = fmaxf(sqrtf(nnb[t + 1]), EPS_);
      sr = dlb[t + 1] / (ncur * nx);
    }
    float shr = (fabsf(sr) < 1e-6f) ? copysignf(1e-6f, sr) : sr;
    float shc = fmaxf(sc, 1e-6f);
    float* ratb = rat + (size_t)b * T_;
    ratb[t] = sl / shr;
    ratb[(size_t)B_ * T_ + t] = shr / shc;
    ratb[(size_t)2 * B_ * T_ + t] = sc;
  } else {
    const int idx = (bid - 128) * 256 + threadIdx.x;
    if (idx >= O_ * KP_) return;
    const int o = idx / KP_;
    const int p = idx - o * KP_;
    const int g = p / 576; const int r = p - g * 576;
    const int k = r / 192; const int j = r - k * 192;
    const int c_lo = (512 * g - k + 2) / 3;
    const int c_hi = (512 * g + 511 - k) / 3;
    const int c = (c_lo & ~7) + j;
    float v = (c >= c_lo && c <= c_hi) ? w[((size_t)o * C_ + c) * 3 + k] : 0.f;
    wbf[idx] = f2bf(v);
  }
}

// ---------------- feature transpose+convert (+ zero pad rows when x==64) -------------
__global__ void transpose_kernel(const float* __restrict__ feat, ushort_t* __restrict__ Ftp) {
  const int b = blockIdx.z;
  const int c0 = blockIdx.y * 64;
  const int tid = threadIdx.x;
  if (blockIdx.x == T_ / 64) {  // pad rows t=-1 (row 0) and t=T (row 4097)
    if (tid < 64)        Ftp[((size_t)b * FTP_ROWS + 0) * 512 + c0 + tid] = 0;
    else if (tid < 128)  Ftp[((size_t)b * FTP_ROWS + T_ + 1) * 512 + c0 + (tid - 64)] = 0;
    return;
  }
  const int t0 = blockIdx.x * 64;
  __shared__ ushort_t LT[64 * 72];
  {
    const int cl = tid >> 2;
    const int tq = (tid & 3) * 16;
    const float* src = feat + ((size_t)b * C_ + c0 + cl) * T_ + t0 + tq;
    for (int q = 0; q < 4; ++q) {
      float4 v = *(const float4*)(src + q * 4);
      const int t = tq + q * 4;
      LT[(t + 0) * 72 + cl] = f2bf(v.x);
      LT[(t + 1) * 72 + cl] = f2bf(v.y);
      LT[(t + 2) * 72 + cl] = f2bf(v.z);
      LT[(t + 3) * 72 + cl] = f2bf(v.w);
    }
  }
  __syncthreads();
  {
    const int tl = tid >> 2;
    const int cq = (tid & 3) * 16;
    ushort_t* dst = Ftp + ((size_t)b * FTP_ROWS + t0 + tl + 1) * 512 + c0 + cq;
    *(uint4*)(dst) = *(const uint4*)&LT[tl * 72 + cq];
    *(uint4*)(dst + 8) = *(const uint4*)&LT[tl * 72 + cq + 8];
  }
}

// ---- main GEMM: m201 8-phase port. 256x256, 8 waves (2Mx4N, 128x64/wave), BK=64,
// ---- k-split half-tiles, 2-barrier phases, vmcnt(4) at p1/p3 only, Horner acc.
__global__ __launch_bounds__(512, 2)
void conv_gemm_kernel(const ushort_t* __restrict__ Ftp,
                      const ushort_t* __restrict__ wbf,
                      const float* __restrict__ rat,
                      float* __restrict__ out) {
  extern __shared__ ushort_t lds[];

  const int b = blockIdx.z;
  const int oBase = blockIdx.y * BM;
  const int tBase = blockIdx.x * BN;

  const int tid = threadIdx.x;
  const int lane = tid & 63;
  const int wid = tid >> 6;           // 8 waves
  const int wm = wid >> 2;            // 0..1 (o, 128 rows)
  const int wn = wid & 3;             // 0..3 (t, 64 cols)
  const int llo = lane & 15, lhi = lane >> 4;

  // read-side chunk swizzle over 4 chunks: chunk = lhi ^ ((row>>1)&3)  (2-way, free)
  const int rsw = (lhi ^ ((llo >> 1) & 3)) * 8;
  const int aRdOff = (wm * 128 + llo) * 32 + rsw;            // + h*8192 + (mh*4+mm)*512
  const int bRdOff = 16384 + (wn * 64 + llo) * 32 + rsw;     // + h*8192 + n*512

  // staging: row = i*128 + wid*16 + (lane>>2); source chunk = (lane&3)^((lane>>3)&3)
  const int schunk = ((lane & 3) ^ ((lane >> 3) & 3)) * 8;
  const int srow = wid * 16 + (lane >> 2);

  const ushort_t* ftpB = Ftp + (size_t)b * FTP_ROWS * 512;

  // ---- rat preload (Horner ratios), pin, drain so vmcnt counts stay exact ----
  const float* ratB = rat + (size_t)b * T_ + tBase + wn * 64 + llo;
  float rv[3][4];
#pragma unroll
  for (int g = 0; g < 3; ++g)
#pragma unroll
    for (int n = 0; n < 4; ++n) {
      rv[g][n] = ratB[(size_t)g * B_ * T_ + n * 16];
      asm volatile("" : "+v"(rv[g][n]));
    }
  asm volatile("s_waitcnt vmcnt(0)" ::: "memory");

  f32x4 acc[8][4];
  const f32x4 vzero = {0.f, 0.f, 0.f, 0.f};
#pragma unroll
  for (int m = 0; m < 8; ++m)
#pragma unroll
    for (int n = 0; n < 4; ++n) acc[m][n] = vzero;

  // ---- stage one half-tile of tile t1: p=0:A-h0, 1:B-h0, 2:A-h1, 3:B-h1 (2 gloads) --
  auto STAGE_HALF = [&](int t1, int p) {
    const int s2 = (t1 < 9) ? t1 : (t1 < 18 ? t1 + 9 : t1 - 9);
    const int h = p >> 1, isB = p & 1;
    const int g = s2 / 9, rr = s2 - g * 9, k = rr / 3, jb = rr - k * 3;
    const int c_st = ((512 * g - k + 2) / 3) & ~7;
    ushort_t* d = lds + (t1 & 1) * BUF_USH + isB * 16384 + h * 8192 + wid * 512;
    if (!isB) {
      const ushort_t* s = wbf + (size_t)(oBase + srow) * KP_ + s2 * 64 + h * 32 + schunk;
      GLOAD16(s, d);
      GLOAD16(s + (size_t)128 * KP_, d + 4096);
    } else {
      const ushort_t* s = ftpB + (size_t)(tBase + srow) * 512 + k * 512 + c_st + jb * 64 + h * 32 + schunk;
      GLOAD16(s, d);
      GLOAD16(s + (size_t)128 * 512, d + 4096);
    }
  };

  // ---- prologue: tile 0 fully staged, collective drain ----
  STAGE_HALF(0, 0); STAGE_HALF(0, 1); STAGE_HALF(0, 2); STAGE_HALF(0, 3);
  asm volatile("s_waitcnt vmcnt(0)" ::: "memory");
  __builtin_amdgcn_s_barrier();
  asm volatile("" ::: "memory");

  bf16x8 bfv[2][4];

#pragma unroll
  for (int t = 0; t < 27; ++t) {
    const uint32_t rb = (uint32_t)(t & 1) * BUF_USH;
#pragma unroll
    for (int p = 0; p < 4; ++p) {
      const int h = p >> 1, mh = p & 1;

      // ds-load this phase's register subtile (latency hides in barrier convergence)
      if (mh == 0) {
#pragma unroll
        for (int n = 0; n < 4; ++n)
          bfv[h][n] = *(const bf16x8*)&lds[rb + h * 8192 + bRdOff + n * 512];
      }
      bf16x8 af[4];
#pragma unroll
      for (int mm = 0; mm < 4; ++mm)
        af[mm] = *(const bf16x8*)&lds[rb + h * 8192 + aRdOff + (mh * 4 + mm) * 512];

      // stage 1 half-tile of tile t+1 into the other buffer
      if (t + 1 < 27) STAGE_HALF(t + 1, p);

      // counted vmcnt only at p1/p3: forces the 2 half-tiles needed 2 phases ahead
      if (p == 1) {
        if (t == 26) { asm volatile("s_waitcnt vmcnt(0)" ::: "memory"); }
        else         { asm volatile("s_waitcnt vmcnt(4)" ::: "memory"); }
      } else if (p == 3 && t < 26) {
        asm volatile("s_waitcnt vmcnt(4)" ::: "memory");
      }
      __builtin_amdgcn_s_barrier();
      asm volatile("s_waitcnt lgkmcnt(0)" ::: "memory");
      __builtin_amdgcn_sched_barrier(0);   // rule #18: keep MFMA below the lgkm wait

      __builtin_amdgcn_s_setprio(1);
#pragma unroll
      for (int mm = 0; mm < 4; ++mm)
#pragma unroll
        for (int n = 0; n < 4; ++n)
          acc[mh * 4 + mm][n] =
              __builtin_amdgcn_mfma_f32_16x16x32_bf16(af[mm], bfv[h][n], acc[mh * 4 + mm][n], 0, 0, 0);
      __builtin_amdgcn_s_setprio(0);

      // Horner group boundaries (group order l, r, c): rescale single accumulator
      if (p == 3 && (t == 8 || t == 17 || t == 26)) {
        const int sel = (t == 8) ? 0 : (t == 17) ? 1 : 2;
#pragma unroll
        for (int n = 0; n < 4; ++n) {
          const float s = rv[sel][n];
#pragma unroll
          for (int m = 0; m < 8; ++m) acc[m][n] *= s;
        }
      }

      __builtin_amdgcn_s_barrier();
      asm volatile("" ::: "memory");
    }
  }

  // ---- epilogue: D layout col=lane&15, row=(lane>>4)*4+reg ----
  float* outB = out + ((size_t)b * O_ + oBase) * T_ + tBase;
#pragma unroll
  for (int m = 0; m < 8; ++m) {
    const int r0 = wm * 128 + m * 16 + lhi * 4;
#pragma unroll
    for (int n = 0; n < 4; ++n) {
      const int cg = wn * 64 + n * 16 + llo;
#pragma unroll
      for (int r = 0; r < 4; ++r)
        outB[(size_t)(r0 + r) * T_ + cg] = acc[m][n][r];
    }
  }
}

extern "C" void kernel_launch(void* const* d_in, const int* in_sizes, int n_in,
                              void* d_out, int out_size, void* d_ws, size_t ws_size,
                              hipStream_t stream) {
  const float* feature   = (const float*)d_in[0];
  const float* embedding = (const float*)d_in[1];
  const float* weight    = (const float*)d_in[2];
  float* out = (float*)d_out;

  float* ws  = (float*)d_ws;
  float* nn  = ws;                                   // B*T f32
  float* dl  = nn + (size_t)B_ * T_;                 // B*T f32
  float* rat = dl + (size_t)B_ * T_;                 // 3*B*T f32 (rl, rr, fin)
  ushort_t* wbf = (ushort_t*)(rat + (size_t)3 * B_ * T_);   // O*KP bf16
  ushort_t* Ftp = wbf + (size_t)O_ * KP_;                   // B*FTP_ROWS*C bf16

  (void)hipFuncSetAttribute((const void*)conv_gemm_kernel,
                            hipFuncAttributeMaxDynamicSharedMemorySize, LDS_BYTES);

  sim_reduce_kernel<<<dim3(T_ / 256, B_), dim3(64, 4), 0, stream>>>(embedding, nn, dl);
  prep_small_kernel<<<dim3(128 + (O_ * KP_ + 255) / 256), 256, 0, stream>>>(nn, dl, rat, weight, wbf);
  transpose_kernel<<<dim3(T_ / 64 + 1, C_ / 64, B_), 256, 0, stream>>>(feature, Ftp);
  conv_gemm_kernel<<<dim3(T_ / BN, O_ / BM, B_), 512, LDS_BYTES, stream>>>(Ftp, wbf, rat, out);
}

// Round 14
// 102.474 us; speedup vs baseline: 1.0178x; 1.0178x over previous
//
#include <hip/hip_runtime.h>
#include <hip/hip_bf16.h>
#include <stdint.h>

#define B_ 8
#define C_ 512
#define T_ 4096
#define O_ 512
#define KP_ 1728   /* padded K: 3 groups x 3 k x 192 */
#define EPS_ 1e-8f

#define BM 256
#define BN 256
#define FTP_ROWS 4104

/* LDS: 2 buffers x [A-h0 8192 | A-h1 8192 | B-h0 8192 | B-h1 8192] ush = 128 KB */
#define BUF_USH 32768
#define LDS_BYTES (2 * BUF_USH * 2)

typedef unsigned short ushort_t;
typedef __attribute__((ext_vector_type(4))) float f32x4;
typedef __attribute__((ext_vector_type(8))) short bf16x8;

__device__ __forceinline__ ushort_t f2bf(float f) {
  union { float f; uint32_t u; } x; x.f = f;
  uint32_t u = x.u;
  uint32_t r = (u + 0x7FFFu + ((u >> 16) & 1u)) >> 16;
  return (ushort_t)r;
}

#define GLOAD16(gsrc, ldst) \
  __builtin_amdgcn_global_load_lds((const __attribute__((address_space(1))) unsigned int*)(gsrc), \
                                   (__attribute__((address_space(3))) unsigned int*)(ldst), 16, 0, 0)

// ---------------- sim reduction: nn[t] = sum_c e^2, dl[t] = sum_c e[t]*e[t-1] ---------
__global__ void sim_reduce_kernel(const float* __restrict__ emb,
                                  float* __restrict__ nn_out,
                                  float* __restrict__ dl_out) {
  const int b = blockIdx.y;
  const int t0 = (blockIdx.x * 64 + threadIdx.x) * 4;
  const int cty = threadIdx.y;
  float nn0=0.f,nn1=0.f,nn2=0.f,nn3=0.f;
  float dl0=0.f,dl1=0.f,dl2=0.f,dl3=0.f;
  const float* base = emb + (size_t)b * C_ * T_;
  for (int c = cty * 128; c < cty * 128 + 128; ++c) {
    const float* row = base + (size_t)c * T_;
    float4 v = *(const float4*)(row + t0);
    float el = (t0 > 0) ? row[t0 - 1] : 0.f;
    nn0 += v.x*v.x; nn1 += v.y*v.y; nn2 += v.z*v.z; nn3 += v.w*v.w;
    dl0 += v.x*el;  dl1 += v.y*v.x; dl2 += v.z*v.y; dl3 += v.w*v.z;
  }
  __shared__ float red[4][64*8];
  float* myr = &red[cty][threadIdx.x * 8];
  if (cty != 0) {
    myr[0]=nn0; myr[1]=nn1; myr[2]=nn2; myr[3]=nn3;
    myr[4]=dl0; myr[5]=dl1; myr[6]=dl2; myr[7]=dl3;
  }
  __syncthreads();
  if (cty == 0) {
    for (int q = 1; q < 4; ++q) {
      float* r = &red[q][threadIdx.x * 8];
      nn0+=r[0]; nn1+=r[1]; nn2+=r[2]; nn3+=r[3];
      dl0+=r[4]; dl1+=r[5]; dl2+=r[6]; dl3+=r[7];
    }
    float* nb = nn_out + (size_t)b * T_ + t0;
    float* db = dl_out + (size_t)b * T_ + t0;
    nb[0]=nn0; nb[1]=nn1; nb[2]=nn2; nb[3]=nn3;
    db[0]=dl0; db[1]=dl1; db[2]=dl2; db[3]=dl3;
  }
}

// ------- fused: Horner-ratio finalize (blocks 0..127) + weight permute (rest) --------
__global__ void prep_small_kernel(const float* __restrict__ nn,
                                  const float* __restrict__ dl,
                                  float* __restrict__ rat,
                                  const float* __restrict__ w,
                                  ushort_t* __restrict__ wbf) {
  const int bid = blockIdx.x;
  if (bid < 128) {
    const int idx = bid * 256 + threadIdx.x;
    const int b = idx >> 12;
    const int t = idx & (T_ - 1);
    const float* nnb = nn + (size_t)b * T_;
    const float* dlb = dl + (size_t)b * T_;
    float nncur = nnb[t];
    float ncur = fmaxf(sqrtf(nncur), EPS_);
    float sc = nncur / (ncur * ncur);
    float sl = 0.f, sr = 0.f;
    if (t > 0) {
      float np = fmaxf(sqrtf(nnb[t - 1]), EPS_);
      sl = dlb[t] / (ncur * np);
    }
    if (t < T_ - 1) {
      float nx = fmaxf(sqrtf(nnb[t + 1]), EPS_);
      sr = dlb[t + 1] / (ncur * nx);
    }
    float shr = (fabsf(sr) < 1e-6f) ? copysignf(1e-6f, sr) : sr;
    float shc = fmaxf(sc, 1e-6f);
    float* ratb = rat + (size_t)b * T_;
    ratb[t] = sl / shr;
    ratb[(size_t)B_ * T_ + t] = shr / shc;
    ratb[(size_t)2 * B_ * T_ + t] = sc;
  } else {
    const int idx = (bid - 128) * 256 + threadIdx.x;
    if (idx >= O_ * KP_) return;
    const int o = idx / KP_;
    const int p = idx - o * KP_;
    const int g = p / 576; const int r = p - g * 576;
    const int k = r / 192; const int j = r - k * 192;
    const int c_lo = (512 * g - k + 2) / 3;
    const int c_hi = (512 * g + 511 - k) / 3;
    const int c = (c_lo & ~7) + j;
    float v = (c >= c_lo && c <= c_hi) ? w[((size_t)o * C_ + c) * 3 + k] : 0.f;
    wbf[idx] = f2bf(v);
  }
}

// ---------------- feature transpose+convert (+ zero pad rows when x==64) -------------
__global__ void transpose_kernel(const float* __restrict__ feat, ushort_t* __restrict__ Ftp) {
  const int b = blockIdx.z;
  const int c0 = blockIdx.y * 64;
  const int tid = threadIdx.x;
  if (blockIdx.x == T_ / 64) {  // pad rows t=-1 (row 0) and t=T (row 4097)
    if (tid < 64)        Ftp[((size_t)b * FTP_ROWS + 0) * 512 + c0 + tid] = 0;
    else if (tid < 128)  Ftp[((size_t)b * FTP_ROWS + T_ + 1) * 512 + c0 + (tid - 64)] = 0;
    return;
  }
  const int t0 = blockIdx.x * 64;
  __shared__ ushort_t LT[64 * 72];
  {
    const int cl = tid >> 2;
    const int tq = (tid & 3) * 16;
    const float* src = feat + ((size_t)b * C_ + c0 + cl) * T_ + t0 + tq;
    for (int q = 0; q < 4; ++q) {
      float4 v = *(const float4*)(src + q * 4);
      const int t = tq + q * 4;
      LT[(t + 0) * 72 + cl] = f2bf(v.x);
      LT[(t + 1) * 72 + cl] = f2bf(v.y);
      LT[(t + 2) * 72 + cl] = f2bf(v.z);
      LT[(t + 3) * 72 + cl] = f2bf(v.w);
    }
  }
  __syncthreads();
  {
    const int tl = tid >> 2;
    const int cq = (tid & 3) * 16;
    ushort_t* dst = Ftp + ((size_t)b * FTP_ROWS + t0 + tl + 1) * 512 + c0 + cq;
    *(uint4*)(dst) = *(const uint4*)&LT[tl * 72 + cq];
    *(uint4*)(dst + 8) = *(const uint4*)&LT[tl * 72 + cq + 8];
  }
}

// ---- main GEMM: m201 8-phase port. 256x256, 8 waves (2Mx4N, 128x64/wave), BK=64,
// ---- k-split half-tiles, 2-barrier phases, vmcnt(4) at p1/p3 only, Horner acc.
__global__ __launch_bounds__(512, 2)
void conv_gemm_kernel(const ushort_t* __restrict__ Ftp,
                      const ushort_t* __restrict__ wbf,
                      const float* __restrict__ rat,
                      float* __restrict__ out) {
  extern __shared__ ushort_t lds[];

  const int b = blockIdx.z;
  const int oBase = blockIdx.y * BM;
  const int tBase = blockIdx.x * BN;

  const int tid = threadIdx.x;
  const int lane = tid & 63;
  const int wid = tid >> 6;           // 8 waves
  const int wm = wid >> 2;            // 0..1 (o, 128 rows)
  const int wn = wid & 3;             // 0..3 (t, 64 cols)
  const int llo = lane & 15, lhi = lane >> 4;

  // read-side chunk swizzle over 4 chunks: chunk = lhi ^ ((row>>1)&3)  (2-way, free)
  const int rsw = (lhi ^ ((llo >> 1) & 3)) * 8;
  const int aRdOff = (wm * 128 + llo) * 32 + rsw;            // + h*8192 + (mh*4+mm)*512
  const int bRdOff = 16384 + (wn * 64 + llo) * 32 + rsw;     // + h*8192 + n*512

  // staging: row = i*128 + wid*16 + (lane>>2); source chunk = (lane&3)^((lane>>3)&3)
  const int schunk = ((lane & 3) ^ ((lane >> 3) & 3)) * 8;
  const int srow = wid * 16 + (lane >> 2);

  const ushort_t* ftpB = Ftp + (size_t)b * FTP_ROWS * 512;

  // ---- rat preload (Horner ratios), pin, drain so vmcnt counts stay exact ----
  const float* ratB = rat + (size_t)b * T_ + tBase + wn * 64 + llo;
  float rv[3][4];
#pragma unroll
  for (int g = 0; g < 3; ++g)
#pragma unroll
    for (int n = 0; n < 4; ++n) {
      rv[g][n] = ratB[(size_t)g * B_ * T_ + n * 16];
      asm volatile("" : "+v"(rv[g][n]));
    }
  asm volatile("s_waitcnt vmcnt(0)" ::: "memory");

  f32x4 acc[8][4];
  const f32x4 vzero = {0.f, 0.f, 0.f, 0.f};
#pragma unroll
  for (int m = 0; m < 8; ++m)
#pragma unroll
    for (int n = 0; n < 4; ++n) acc[m][n] = vzero;

  // ---- stage one half-tile of tile t1: p=0:A-h0, 1:B-h0, 2:A-h1, 3:B-h1 (2 gloads) --
  auto STAGE_HALF = [&](int t1, int p) {
    const int s2 = (t1 < 9) ? t1 : (t1 < 18 ? t1 + 9 : t1 - 9);
    const int h = p >> 1, isB = p & 1;
    const int g = s2 / 9, rr = s2 - g * 9, k = rr / 3, jb = rr - k * 3;
    const int c_st = ((512 * g - k + 2) / 3) & ~7;
    ushort_t* d = lds + (t1 & 1) * BUF_USH + isB * 16384 + h * 8192 + wid * 512;
    if (!isB) {
      const ushort_t* s = wbf + (size_t)(oBase + srow) * KP_ + s2 * 64 + h * 32 + schunk;
      GLOAD16(s, d);
      GLOAD16(s + (size_t)128 * KP_, d + 4096);
    } else {
      const ushort_t* s = ftpB + (size_t)(tBase + srow) * 512 + k * 512 + c_st + jb * 64 + h * 32 + schunk;
      GLOAD16(s, d);
      GLOAD16(s + (size_t)128 * 512, d + 4096);
    }
  };

  // ---- prologue: tile 0 fully staged, collective drain ----
  STAGE_HALF(0, 0); STAGE_HALF(0, 1); STAGE_HALF(0, 2); STAGE_HALF(0, 3);
  asm volatile("s_waitcnt vmcnt(0)" ::: "memory");
  __builtin_amdgcn_s_barrier();
  asm volatile("" ::: "memory");

  bf16x8 bfv[2][4];

#pragma unroll
  for (int t = 0; t < 27; ++t) {
    const uint32_t rb = (uint32_t)(t & 1) * BUF_USH;
#pragma unroll
    for (int p = 0; p < 4; ++p) {
      const int h = p >> 1, mh = p & 1;

      // ds-load this phase's register subtile (latency hides in barrier convergence)
      if (mh == 0) {
#pragma unroll
        for (int n = 0; n < 4; ++n)
          bfv[h][n] = *(const bf16x8*)&lds[rb + h * 8192 + bRdOff + n * 512];
      }
      bf16x8 af[4];
#pragma unroll
      for (int mm = 0; mm < 4; ++mm)
        af[mm] = *(const bf16x8*)&lds[rb + h * 8192 + aRdOff + (mh * 4 + mm) * 512];

      // stage 1 half-tile of tile t+1 into the other buffer
      if (t + 1 < 27) STAGE_HALF(t + 1, p);

      // counted vmcnt only at p1/p3: forces the 2 half-tiles needed 2 phases ahead
      if (p == 1) {
        if (t == 26) { asm volatile("s_waitcnt vmcnt(0)" ::: "memory"); }
        else         { asm volatile("s_waitcnt vmcnt(4)" ::: "memory"); }
      } else if (p == 3 && t < 26) {
        asm volatile("s_waitcnt vmcnt(4)" ::: "memory");
      }
      __builtin_amdgcn_s_barrier();
      asm volatile("s_waitcnt lgkmcnt(0)" ::: "memory");
      __builtin_amdgcn_sched_barrier(0);   // rule #18: keep MFMA below the lgkm wait

      __builtin_amdgcn_s_setprio(1);
#pragma unroll
      for (int mm = 0; mm < 4; ++mm)
#pragma unroll
        for (int n = 0; n < 4; ++n)
          acc[mh * 4 + mm][n] =
              __builtin_amdgcn_mfma_f32_16x16x32_bf16(af[mm], bfv[h][n], acc[mh * 4 + mm][n], 0, 0, 0);
      __builtin_amdgcn_s_setprio(0);

      // Horner group boundaries (group order l, r, c): rescale single accumulator
      if (p == 3 && (t == 8 || t == 17 || t == 26)) {
        const int sel = (t == 8) ? 0 : (t == 17) ? 1 : 2;
#pragma unroll
        for (int n = 0; n < 4; ++n) {
          const float s = rv[sel][n];
#pragma unroll
          for (int m = 0; m < 8; ++m) acc[m][n] *= s;
        }
      }

      __builtin_amdgcn_s_barrier();
      asm volatile("" ::: "memory");
    }
  }

  // ---- epilogue: D layout col=lane&15, row=(lane>>4)*4+reg ----
  float* outB = out + ((size_t)b * O_ + oBase) * T_ + tBase;
#pragma unroll
  for (int m = 0; m < 8; ++m) {
    const int r0 = wm * 128 + m * 16 + lhi * 4;
#pragma unroll
    for (int n = 0; n < 4; ++n) {
      const int cg = wn * 64 + n * 16 + llo;
#pragma unroll
      for (int r = 0; r < 4; ++r)
        outB[(size_t)(r0 + r) * T_ + cg] = acc[m][n][r];
    }
  }
}

extern "C" void kernel_launch(void* const* d_in, const int* in_sizes, int n_in,
                              void* d_out, int out_size, void* d_ws, size_t ws_size,
                              hipStream_t stream) {
  const float* feature   = (const float*)d_in[0];
  const float* embedding = (const float*)d_in[1];
  const float* weight    = (const float*)d_in[2];
  float* out = (float*)d_out;

  float* ws  = (float*)d_ws;
  float* nn  = ws;                                   // B*T f32
  float* dl  = nn + (size_t)B_ * T_;                 // B*T f32
  float* rat = dl + (size_t)B_ * T_;                 // 3*B*T f32 (rl, rr, fin)
  ushort_t* wbf = (ushort_t*)(rat + (size_t)3 * B_ * T_);   // O*KP bf16
  ushort_t* Ftp = wbf + (size_t)O_ * KP_;                   // B*FTP_ROWS*C bf16

  (void)hipFuncSetAttribute((const void*)conv_gemm_kernel,
                            hipFuncAttributeMaxDynamicSharedMemorySize, LDS_BYTES);

  sim_reduce_kernel<<<dim3(T_ / 256, B_), dim3(64, 4), 0, stream>>>(embedding, nn, dl);
  prep_small_kernel<<<dim3(128 + (O_ * KP_ + 255) / 256), 256, 0, stream>>>(nn, dl, rat, weight, wbf);
  transpose_kernel<<<dim3(T_ / 64 + 1, C_ / 64, B_), 256, 0, stream>>>(feature, Ftp);
  conv_gemm_kernel<<<dim3(T_ / BN, O_ / BM, B_), 512, LDS_BYTES, stream>>>(Ftp, wbf, rat, out);
}